// Round 9
// baseline (1749.036 us; speedup 1.0000x reference)
//
#include <hip/hip_runtime.h>
#include <hip/hip_bf16.h>
#include <math.h>

#define NN 50000
#define EE 200000
#define ET 250000   // EE + NN self loops
#define GG 64
#define LL 6

using short8 = __attribute__((ext_vector_type(8))) short;
using f32x4  = __attribute__((ext_vector_type(4))) float;
typedef unsigned short ushortT;

__device__ __forceinline__ float elu1(float x) { return x > 0.f ? x : expm1f(x); }
__device__ __forceinline__ float gelu_exact(float x) {
    return 0.5f * x * (1.f + erff(x * 0.70710678118654752440f));
}
__device__ __forceinline__ short f2bf(float f) {
    __hip_bfloat16 h = __float2bfloat16(f);
    return *reinterpret_cast<short*>(&h);
}
__device__ __forceinline__ float bf2f(ushortT u) {
    return __uint_as_float(((unsigned)u) << 16);
}

// ---------------- CSR build ----------------
__global__ void count_deg_kernel(const int* __restrict__ ei, int* __restrict__ deg) {
    int e = blockIdx.x * 256 + threadIdx.x;
    if (e >= ET) return;
    int dst = (e < EE) ? ei[EE + e] : (e - EE);
    atomicAdd(&deg[dst], 1);
}

__global__ void scan_kernel(const int* __restrict__ deg, int* __restrict__ row_ptr, int n) {
    __shared__ int s[1024];
    int tid = threadIdx.x;
    const int per = (n + 1023) / 1024;
    int lo = tid * per, hi = min(lo + per, n);
    int sum = 0;
    for (int i = lo; i < hi; i++) sum += deg[i];
    s[tid] = sum;
    __syncthreads();
    for (int off = 1; off < 1024; off <<= 1) {
        int t = (tid >= off) ? s[tid - off] : 0;
        __syncthreads();
        s[tid] += t;
        __syncthreads();
    }
    int run = s[tid] - sum;
    for (int i = lo; i < hi; i++) { row_ptr[i] = run; run += deg[i]; }
    if (tid == 1023) row_ptr[n] = s[1023];
}

__global__ void fill_csr_kernel(const int* __restrict__ ei, const int* __restrict__ row_ptr,
                                int* __restrict__ cursor, int* __restrict__ edge_src) {
    int e = blockIdx.x * 256 + threadIdx.x;
    if (e >= ET) return;
    int src, dst;
    if (e < EE) { src = ei[e]; dst = ei[EE + e]; }
    else        { src = e - EE; dst = e - EE; }
    int pos = atomicAdd(&cursor[dst], 1);
    edge_src[row_ptr[dst] + pos] = src;
}

__global__ void dinv_kernel(const int* __restrict__ row_ptr, float* __restrict__ dinv) {
    int n = blockIdx.x * 256 + threadIdx.x;
    if (n >= NN) return;
    int d = row_ptr[n + 1] - row_ptr[n];
    dinv[n] = (d > 0) ? rsqrtf((float)d) : 0.f;
}

// ---- fold wv into wo: Wvo = wv@wo, bvo = bv@wo + bo (fp32, exact) ----
__global__ void wvwo_kernel(const float* __restrict__ wv, const float* __restrict__ wo,
                            const float* __restrict__ bv, const float* __restrict__ bo,
                            float* __restrict__ Wvo, float* __restrict__ bvo) {
    int l = blockIdx.y;
    const float* Wv = wv + l * 16384;
    const float* Wo = wo + l * 16384;
    int tid = blockIdx.x * 256 + threadIdx.x;
    if (tid < 16384) {
        int r = tid >> 7, c = tid & 127;
        float s = 0.f;
        for (int k = 0; k < 128; k++) s += Wv[r * 128 + k] * Wo[k * 128 + c];
        Wvo[l * 16384 + tid] = s;
    }
    if (blockIdx.x == 0 && threadIdx.x < 128) {
        int c = threadIdx.x;
        float s = bo[l * 128 + c];
        for (int k = 0; k < 128; k++) s += bv[l * 128 + k] * Wo[k * 128 + c];
        bvo[l * 128 + c] = s;
    }
}

// ---- weight prep: fp32 [K,N] (ldb) -> bf16 MFMA B-fragment order ----
// Bp[((c16*(K/32)+kb)*64 + l)*8 + j] = B[kb*32 + (l>>4)*8 + j][c16*16 + (l&15)]
__global__ void bprep_kernel(const float* __restrict__ B, short* __restrict__ Bp,
                             int K, int N, int ldb, long srcStride) {
    int layer = blockIdx.y;
    const float* Bsrc = B + srcStride * layer;
    short* Bd = Bp + (size_t)K * N * layer;
    int total = (K >> 5) * (N >> 4) * 64;
    int tid = blockIdx.x * 256 + threadIdx.x;
    if (tid >= total) return;
    int l = tid & 63;
    int rest = tid >> 6;
    int kbc = K >> 5;
    int kb = rest % kbc;
    int c16 = rest / kbc;
    int n = c16 * 16 + (l & 15);
    int kbase = kb * 32 + (l >> 4) * 8;
    short v[8];
#pragma unroll
    for (int j = 0; j < 8; j++) v[j] = f2bf(Bsrc[(size_t)(kbase + j) * ldb + n]);
    *(uint4*)(Bd + (size_t)tid * 8) = *(uint4*)v;
}

__global__ void cast_bf16_kernel(const float* __restrict__ in, short* __restrict__ out, int n4) {
    int i = blockIdx.x * 256 + threadIdx.x;
    if (i >= n4) return;
    float4 v = *(const float4*)(in + (size_t)i * 4);
    short s[4] = { f2bf(v.x), f2bf(v.y), f2bf(v.z), f2bf(v.w) };
    *(uint2*)(out + (size_t)i * 4) = *(uint2*)s;
}

// ---------------- MFMA GEMM, LDS-free, RT=1, XCD-aware swizzle --------------
// 64-row blocks (16 rows/wave). grid.x = NSPLIT * MBpad8. xcd = bx&7: all
// NSPLIT column tiles of one row band land on one XCD -> A band L2-resident.
// EPI: 0 plain, 2 asad + store.
template <int EPI, bool OUTBF16, int NSPLIT, int KBC>
__global__ __launch_bounds__(256) void gemm_bf16_kernel(
    const short* __restrict__ A, const short* __restrict__ Bp,
    void* __restrict__ Cv,
    const float* __restrict__ a_s, const float* __restrict__ a_d,
    float* __restrict__ as_out, float* __restrict__ ad_out, int asH,
    int M, int K, int Nc) {
    int t = threadIdx.x;
    int w = t >> 6, l = t & 63;
    int ln = l & 15, lq = l >> 4;
    int MBceil = (M + 63) >> 6;
    int bx = blockIdx.x;
    int xcd = bx & 7, idx = bx >> 3;
    int t2 = idx % NSPLIT;
    int mb = (idx / NSPLIT) * 8 + xcd;
    if (mb >= MBceil) return;
    int bm = mb * 64 + w * 16;
    int arow = bm + ln;
    bool aok = arow < M;
    int rowb = bm + lq * 4;
    const short* Ap = A + (size_t)arow * K + lq * 8;

    f32x4 acc[8];
#pragma unroll
    for (int j = 0; j < 8; j++) acc[j] = (f32x4){0.f, 0.f, 0.f, 0.f};

    if constexpr (KBC > 0) {
        short8 af[KBC];
#pragma unroll
        for (int kb = 0; kb < KBC; kb++)
            af[kb] = aok ? *(const short8*)(Ap + kb * 32) : (short8){0,0,0,0,0,0,0,0};
#pragma unroll
        for (int kb = 0; kb < KBC; kb++)
#pragma unroll
            for (int ct = 0; ct < 8; ct++) {
                short8 bfr = *(const short8*)(Bp + (((size_t)(t2 * 8 + ct) * KBC + kb) * 64 + l) * 8);
                acc[ct] = __builtin_amdgcn_mfma_f32_16x16x32_bf16(af[kb], bfr, acc[ct], 0, 0, 0);
            }
    } else {
        int kbc = K >> 5;
        for (int kb = 0; kb < kbc; kb++) {
            short8 af = aok ? *(const short8*)(Ap + kb * 32) : (short8){0,0,0,0,0,0,0,0};
#pragma unroll
            for (int ct = 0; ct < 8; ct++) {
                short8 bfr = *(const short8*)(Bp + (((size_t)(t2 * 8 + ct) * kbc + kb) * 64 + l) * 8);
                acc[ct] = __builtin_amdgcn_mfma_f32_16x16x32_bf16(af, bfr, acc[ct], 0, 0, 0);
            }
        }
    }

    if (EPI == 2) {
        const float* asv = a_s + t2 * 128;
        const float* adv = a_d + t2 * 128;
#pragma unroll
        for (int reg = 0; reg < 4; reg++) {
            float vs = 0.f, vd = 0.f;
#pragma unroll
            for (int ct = 0; ct < 8; ct++) {
                int colL = ct * 16 + ln;
                float av = acc[ct][reg];
                vs += av * asv[colL];
                vd += av * adv[colL];
            }
            vs += __shfl_xor(vs, 1); vs += __shfl_xor(vs, 2);
            vs += __shfl_xor(vs, 4); vs += __shfl_xor(vs, 8);
            vd += __shfl_xor(vd, 1); vd += __shfl_xor(vd, 2);
            vd += __shfl_xor(vd, 4); vd += __shfl_xor(vd, 8);
            int row = rowb + reg;
            if (ln == 0 && row < M) {
                as_out[(size_t)row * asH + t2] = vs;
                ad_out[(size_t)row * asH + t2] = vd;
            }
        }
    }
#pragma unroll
    for (int ct = 0; ct < 8; ct++) {
        int col = t2 * 128 + ct * 16 + ln;
#pragma unroll
        for (int reg = 0; reg < 4; reg++) {
            int row = rowb + reg;
            if (row < M) {
                float v = acc[ct][reg];
                if (OUTBF16)
                    ((__hip_bfloat16*)Cv)[(size_t)row * Nc + col] = __float2bfloat16(v);
                else
                    ((float*)Cv)[(size_t)row * Nc + col] = v;
            }
        }
    }
}

// ---------------- fused 6-layer transformer (seq_len=1) ---------------------
// Each wave owns 16 rows; state lives in per-wave LDS [16][130] bf16.
// No barriers needed (no cross-wave sharing; DS ops are in-order per wave).
// Per layer: acc=h@Wvo -> +bvo+resid+LN1 -> h ; FFN in 4 col-chunks:
// gelu(h@wf1_c+bf1_c) -> LDS transpose -> out += @wf2_c ; +bf2+resid+LN2 -> h.
__device__ __forceinline__ void ln_resid_lds(
    f32x4 (&acc)[8], const float* __restrict__ bias,
    const float* __restrict__ g, const float* __restrict__ b,
    short (*hw)[130], int lq, int ln,
    float* __restrict__ fQ, int base, int M) {
    float v[8][4];
#pragma unroll
    for (int ct = 0; ct < 8; ct++) {
        int col = ct * 16 + ln;
        float bb = bias[col];
#pragma unroll
        for (int reg = 0; reg < 4; reg++)
            v[ct][reg] = acc[ct][reg] + bb + bf2f((ushortT)hw[lq * 4 + reg][col]);
    }
#pragma unroll
    for (int reg = 0; reg < 4; reg++) {
        float s = 0.f;
#pragma unroll
        for (int ct = 0; ct < 8; ct++) s += v[ct][reg];
        s += __shfl_xor(s, 1); s += __shfl_xor(s, 2);
        s += __shfl_xor(s, 4); s += __shfl_xor(s, 8);
        float mean = s * (1.f / 128.f);
        float s2 = 0.f;
#pragma unroll
        for (int ct = 0; ct < 8; ct++) { float d = v[ct][reg] - mean; s2 += d * d; }
        s2 += __shfl_xor(s2, 1); s2 += __shfl_xor(s2, 2);
        s2 += __shfl_xor(s2, 4); s2 += __shfl_xor(s2, 8);
        float rstd = rsqrtf(s2 * (1.f / 128.f) + 1e-5f);
        int row = lq * 4 + reg;
#pragma unroll
        for (int ct = 0; ct < 8; ct++) {
            int col = ct * 16 + ln;
            float o = (v[ct][reg] - mean) * rstd * g[col] + b[col];
            hw[row][col] = f2bf(o);
            if (fQ) {
                int grow = base + row;
                if (grow < M) fQ[(size_t)grow * 128 + col] = o;
            }
        }
    }
}

__global__ __launch_bounds__(256) void transformer_fused_kernel(
    const ushortT* __restrict__ Qin,
    const short* __restrict__ Wvop, const float* __restrict__ bvo,
    const short* __restrict__ wf1p, const float* __restrict__ bf1,
    const short* __restrict__ wf2p, const float* __restrict__ bf2,
    const float* __restrict__ ln1g, const float* __restrict__ ln1b,
    const float* __restrict__ ln2g, const float* __restrict__ ln2b,
    float* __restrict__ fQ, int M) {
    __shared__ short hS[4][16][130];
    __shared__ short dS[4][16][130];
    int t = threadIdx.x;
    int w = t >> 6, l = t & 63;
    int ln = l & 15, lq = l >> 4;
    int base = blockIdx.x * 64 + w * 16;
    short (*hw)[130] = hS[w];
    short (*dw)[130] = dS[w];

    // load state: 16 rows x 128 cols bf16, coalesced uint4
#pragma unroll
    for (int i = 0; i < 4; i++) {
        int j = i * 64 + l;
        int r = j >> 4, c8 = j & 15;
        int gr = base + r;
        uint4 u = make_uint4(0, 0, 0, 0);
        if (gr < M) u = *(const uint4*)(Qin + (size_t)gr * 128 + c8 * 8);
        *(uint4*)&hw[r][c8 * 8] = u;
    }

    for (int layer = 0; layer < LL; layer++) {
        const short* Wv = Wvop + layer * 16384;
        const short* F1 = wf1p + layer * 65536;
        const short* F2 = wf2p + layer * 65536;
        // ---- attn (folded): acc = h @ Wvo
        short8 af[4];
#pragma unroll
        for (int kb = 0; kb < 4; kb++)
            af[kb] = *(const short8*)&hw[ln][kb * 32 + lq * 8];
        f32x4 acc[8];
#pragma unroll
        for (int j = 0; j < 8; j++) acc[j] = (f32x4){0.f, 0.f, 0.f, 0.f};
#pragma unroll
        for (int kb = 0; kb < 4; kb++)
#pragma unroll
            for (int ct = 0; ct < 8; ct++) {
                short8 bfr = *(const short8*)(Wv + ((ct * 4 + kb) * 64 + l) * 8);
                acc[ct] = __builtin_amdgcn_mfma_f32_16x16x32_bf16(af[kb], bfr, acc[ct], 0, 0, 0);
            }
        ln_resid_lds(acc, bvo + layer * 128, ln1g + layer * 128, ln1b + layer * 128,
                     hw, lq, ln, nullptr, base, M);
        // ---- FFN
#pragma unroll
        for (int kb = 0; kb < 4; kb++)
            af[kb] = *(const short8*)&hw[ln][kb * 32 + lq * 8];
        f32x4 out[8];
#pragma unroll
        for (int j = 0; j < 8; j++) out[j] = (f32x4){0.f, 0.f, 0.f, 0.f};
        const float* bf1l = bf1 + layer * 512;
#pragma unroll
        for (int c = 0; c < 4; c++) {
            // hidden chunk: gelu(h@wf1_c + bf1_c) -> dS (C-layout writes)
#pragma unroll
            for (int ct = 0; ct < 8; ct++) {
                f32x4 h4 = (f32x4){0.f, 0.f, 0.f, 0.f};
#pragma unroll
                for (int kb = 0; kb < 4; kb++) {
                    short8 bfr = *(const short8*)(F1 + (((c * 8 + ct) * 4 + kb) * 64 + l) * 8);
                    h4 = __builtin_amdgcn_mfma_f32_16x16x32_bf16(af[kb], bfr, h4, 0, 0, 0);
                }
                int col = ct * 16 + ln;
                float bb = bf1l[c * 128 + col];
#pragma unroll
                for (int reg = 0; reg < 4; reg++)
                    dw[lq * 4 + reg][col] = f2bf(gelu_exact(h4[reg] + bb));
            }
            // out += hidden_c @ wf2_c
            short8 hf[4];
#pragma unroll
            for (int kb = 0; kb < 4; kb++)
                hf[kb] = *(const short8*)&dw[ln][kb * 32 + lq * 8];
#pragma unroll
            for (int ct = 0; ct < 8; ct++)
#pragma unroll
                for (int kb = 0; kb < 4; kb++) {
                    short8 bfr = *(const short8*)(F2 + ((ct * 16 + c * 4 + kb) * 64 + l) * 8);
                    out[ct] = __builtin_amdgcn_mfma_f32_16x16x32_bf16(hf[kb], bfr, out[ct], 0, 0, 0);
                }
        }
        ln_resid_lds(out, bf2 + layer * 128, ln2g + layer * 128, ln2b + layer * 128,
                     hw, lq, ln, (layer == LL - 1) ? fQ : nullptr, base, M);
    }
}

// ---- fused multi-head GAT softmax-aggregate: one block per node ------------
template <int H, int CPT>
__global__ __launch_bounds__(256) void gat_agg_fused_kernel(
    const ushortT* __restrict__ hpre, const float* __restrict__ as_,
    const float* __restrict__ ad_, const float* __restrict__ bias,
    const int* __restrict__ row_ptr, const int* __restrict__ edge_src,
    __hip_bfloat16* __restrict__ out, int n_nodes) {
    int node = blockIdx.x;
    if (node >= n_nodes) return;
    int t = threadIdx.x;
    int c0 = t * CPT;
    int hb = c0 >> 7;
    int start = row_ptr[node];
    int deg = row_ptr[node + 1] - start;
    float adn = ad_[(size_t)node * H + hb];
    float m = -1e30f, S = 0.f;
    float acc[CPT];
#pragma unroll
    for (int c = 0; c < CPT; c++) acc[c] = 0.f;
    for (int j = 0; j < deg; j++) {
        int s = edge_src[start + j];
        float e = as_[(size_t)s * H + hb] + adn;
        e = e > 0.f ? e : 0.2f * e;
        float mn = fmaxf(m, e);
        float sc = expf(m - mn);
        float wj = expf(e - mn);
        S = S * sc + wj;
        const ushortT* hp = hpre + (size_t)s * (H * 128) + c0;
        float hv[CPT];
        if (CPT == 4) {
            uint2 u = *(const uint2*)hp;
            hv[0] = bf2f((ushortT)(u.x & 0xffff)); hv[1] = bf2f((ushortT)(u.x >> 16));
            hv[2] = bf2f((ushortT)(u.y & 0xffff)); hv[3] = bf2f((ushortT)(u.y >> 16));
        } else {
            unsigned u = *(const unsigned*)hp;
            hv[0] = bf2f((ushortT)(u & 0xffff)); hv[1] = bf2f((ushortT)(u >> 16));
        }
#pragma unroll
        for (int c = 0; c < CPT; c++) acc[c] = acc[c] * sc + wj * hv[c];
        m = mn;
    }
    float inv = 1.f / (S + 1e-16f);
#pragma unroll
    for (int c = 0; c < CPT; c++)
        out[(size_t)node * (H * 128) + c0 + c] =
            __float2bfloat16(elu1(acc[c] * inv + bias[c0 + c]));
}

// ---------------- GCN aggregation (bf16 in) -> bf16 Qb only -----------------
__global__ __launch_bounds__(256) void gcn_agg_kernel(
    const ushortT* __restrict__ hp, const float* __restrict__ dinv,
    const float* __restrict__ b3, const int* __restrict__ row_ptr,
    const int* __restrict__ edge_src,
    __hip_bfloat16* __restrict__ outb, int n_nodes) {
    int node = blockIdx.x * 2 + (threadIdx.x >> 7);
    int c = threadIdx.x & 127;
    if (node >= n_nodes) return;
    int start = row_ptr[node];
    int deg = row_ptr[node + 1] - start;
    float dn = dinv[node];
    float acc = 0.f;
    for (int j = 0; j < deg; j++) {
        int s = edge_src[start + j];
        acc += dinv[s] * dn * bf2f(hp[(size_t)s * 128 + c]);
    }
    outb[(size_t)node * 128 + c] = __float2bfloat16(elu1(acc + b3[c]));
}

// ---------------- pooling ----------------
__global__ void pool1_kernel(const float* __restrict__ Q, const int* __restrict__ batch,
                             float* __restrict__ psum, float* __restrict__ pmax, int n_nodes) {
    int g = blockIdx.x, seg = blockIdx.y;
    int c = threadIdx.x;
    int lo, hi;
    {
        int l = 0, h = n_nodes;
        while (l < h) { int mid = (l + h) >> 1; if (batch[mid] < g) l = mid + 1; else h = mid; }
        lo = l;
        l = lo; h = n_nodes;
        while (l < h) { int mid = (l + h) >> 1; if (batch[mid] < g + 1) l = mid + 1; else h = mid; }
        hi = l;
    }
    int len = hi - lo;
    int a = lo + (int)((long)len * seg / 8);
    int b = lo + (int)((long)len * (seg + 1) / 8);
    float s = 0.f, mx = -INFINITY;
    for (int n = a; n < b; n++) {
        float v = Q[(size_t)n * 128 + c];
        s += v;
        mx = fmaxf(mx, v);
    }
    psum[(g * 8 + seg) * 128 + c] = s;
    pmax[(g * 8 + seg) * 128 + c] = mx;
}

__global__ void pool2_kernel(const float* __restrict__ psum, const float* __restrict__ pmax,
                             const int* __restrict__ batch,
                             const float* __restrict__ bn1g, const float* __restrict__ bn1b,
                             float* __restrict__ hc, int n_nodes) {
    int g = blockIdx.x;
    int c = threadIdx.x;
    int lo, hi;
    {
        int l = 0, h = n_nodes;
        while (l < h) { int mid = (l + h) >> 1; if (batch[mid] < g) l = mid + 1; else h = mid; }
        lo = l;
        l = lo; h = n_nodes;
        while (l < h) { int mid = (l + h) >> 1; if (batch[mid] < g + 1) l = mid + 1; else h = mid; }
        hi = l;
    }
    int cnt = hi - lo;
    float s = 0.f, mx = -INFINITY;
    for (int seg = 0; seg < 8; seg++) {
        s += psum[(g * 8 + seg) * 128 + c];
        mx = fmaxf(mx, pmax[(g * 8 + seg) * 128 + c]);
    }
    float hm = s / fmaxf((float)cnt, 1.f);
    float hx = (cnt > 0 && isfinite(mx)) ? mx : 0.f;
    const float bn_s = 0.99999500003749968f;
    hc[g * 256 + c]       = hm * bn_s * bn1g[c] + bn1b[c];
    hc[g * 256 + 128 + c] = hx * bn_s * bn1g[128 + c] + bn1b[128 + c];
}

__global__ void head_kernel(const float* __restrict__ hc,
                            const float* __restrict__ fc1w, const float* __restrict__ fc1b,
                            const float* __restrict__ bn2g, const float* __restrict__ bn2b,
                            const float* __restrict__ fc2w, const float* __restrict__ fc2b,
                            float* __restrict__ out) {
    int g = blockIdx.x;
    int j = threadIdx.x;
    const float bn_s = 0.99999500003749968f;
    float acc = fc1b[j];
    for (int i = 0; i < 256; i++) acc += hc[g * 256 + i] * fc1w[i * 64 + j];
    acc = elu1(acc);
    acc = acc * bn_s * bn2g[j] + bn2b[j];
    __shared__ float sv[64];
    sv[j] = acc;
    __syncthreads();
    if (j < 2) {
        float o = fc2b[j];
        for (int i = 0; i < 64; i++) o += sv[i] * fc2w[i * 2 + j];
        out[g * 2 + j] = o;
    }
}

// ---------------- launch ----------------
extern "C" void kernel_launch(void* const* d_in, const int* in_sizes, int n_in,
                              void* d_out, int out_size, void* d_ws, size_t ws_size,
                              hipStream_t stream) {
    const float* x    = (const float*)d_in[0];
    const int*   ei   = (const int*)d_in[1];
    const int*   batch= (const int*)d_in[2];
    const float* W1   = (const float*)d_in[3];
    const float* as1  = (const float*)d_in[4];
    const float* ad1  = (const float*)d_in[5];
    const float* b1   = (const float*)d_in[6];
    const float* W2   = (const float*)d_in[7];
    const float* as2  = (const float*)d_in[8];
    const float* ad2  = (const float*)d_in[9];
    const float* b2   = (const float*)d_in[10];
    const float* W3   = (const float*)d_in[11];
    const float* b3   = (const float*)d_in[12];
    const float* wv   = (const float*)d_in[17];
    const float* bv   = (const float*)d_in[18];
    const float* wo   = (const float*)d_in[19];
    const float* bo   = (const float*)d_in[20];
    const float* ln1g = (const float*)d_in[21];
    const float* ln1b = (const float*)d_in[22];
    const float* ln2g = (const float*)d_in[23];
    const float* ln2b = (const float*)d_in[24];
    const float* wf1  = (const float*)d_in[25];
    const float* bf1  = (const float*)d_in[26];
    const float* wf2  = (const float*)d_in[27];
    const float* bf2  = (const float*)d_in[28];
    const float* bn1g = (const float*)d_in[29];
    const float* bn1b = (const float*)d_in[30];
    const float* fc1w = (const float*)d_in[31];
    const float* fc1b = (const float*)d_in[32];
    const float* bn2g = (const float*)d_in[33];
    const float* bn2b = (const float*)d_in[34];
    const float* fc2w = (const float*)d_in[35];
    const float* fc2b = (const float*)d_in[36];
    float* out = (float*)d_out;

    // ---- workspace layout (bytes), peak ~227 MB ----
    char* wsb = (char*)d_ws;
    short* xb    = (short*)wsb;                        // [N,128] bf16
    short* h1pre = (short*)(wsb + 12800000);           // [N,1024] bf16
    short* h2pre = (short*)(wsb + 12800000);           // [N,512] (h1pre dead)
    short* h3pre = (short*)(wsb + 12800000);           // [N,128] (h2pre dead)
    short* bh1   = (short*)(wsb + 115200000);          // [N,1024] bf16
    short* bh2   = (short*)(wsb + 115200000);          // [N,512] (bh1 dead)
    float* fQ    = (float*)(wsb + 128000000);          // [N,128] fp32 (final state)
    short* Qb    = (short*)(wsb + 153600000);          // [N,128] bf16
    char* tail = wsb + 217600000;
    short* W1p  = (short*)tail;  tail += 262144;       // 128x1024
    short* W2p  = (short*)tail;  tail += 1048576;      // 1024x512
    short* W3p  = (short*)tail;  tail += 131072;       // 512x128
    short* Wvop = (short*)tail;  tail += 196608;       // 6 x 128x128
    short* wf1p = (short*)tail;  tail += 786432;       // 6 x 128x512
    short* wf2p = (short*)tail;  tail += 786432;       // 6 x 512x128
    float* Wvo  = (float*)tail;  tail += 393216;       // 6 x 128x128 fp32
    float* bvo  = (float*)tail;  tail += 3072;         // 6 x 128 fp32
    float* fAS  = (float*)tail;  tail += 1600000;      // [N,8]
    float* fAD  = (float*)tail;  tail += 1600000;      // [N,8]
    float* fDv  = (float*)tail;  tail += 200000;
    float* psum = (float*)tail;  tail += 262144;
    float* pmax = (float*)tail;  tail += 262144;
    float* fHC  = (float*)tail;  tail += 65536;
    int* iDeg   = (int*)tail;    tail += 200000;
    int* iRP    = (int*)tail;    tail += 200004;
    int* iCur   = (int*)tail;    tail += 200000;
    int* iES    = (int*)tail;    tail += 1000000;

    hipMemsetAsync(iDeg, 0, NN * sizeof(int), stream);
    hipMemsetAsync(iCur, 0, NN * sizeof(int), stream);

    count_deg_kernel<<<(ET + 255) / 256, 256, 0, stream>>>(ei, iDeg);
    scan_kernel<<<1, 1024, 0, stream>>>(iDeg, iRP, NN);
    fill_csr_kernel<<<(ET + 255) / 256, 256, 0, stream>>>(ei, iRP, iCur, iES);
    dinv_kernel<<<(NN + 255) / 256, 256, 0, stream>>>(iRP, fDv);

    wvwo_kernel<<<dim3(64, 6), 256, 0, stream>>>(wv, wo, bv, bo, Wvo, bvo);
    auto bprep = [&](const float* B, short* Bp, int K, int N, int ldb, long sStride, int layers) {
        int total = (K >> 5) * (N >> 4) * 64;
        dim3 grid((total + 255) / 256, layers);
        bprep_kernel<<<grid, 256, 0, stream>>>(B, Bp, K, N, ldb, sStride);
    };
    bprep(W1, W1p, 128, 1024, 1024, 0, 1);
    bprep(W2, W2p, 1024, 512, 512, 0, 1);
    bprep(W3, W3p, 512, 128, 128, 0, 1);
    bprep(Wvo, Wvop, 128, 128, 128, 16384, 6);
    bprep(wf1, wf1p, 128, 512, 512, 65536, 6);
    bprep(wf2, wf2p, 512, 128, 128, 65536, 6);
    cast_bf16_kernel<<<(NN * 128 / 4 + 255) / 256, 256, 0, stream>>>(x, xb, NN * 128 / 4);

    // 64-row blocks, padded to multiple of 8 row-bands for the XCD swizzle
    const int MB64 = (NN + 63) / 64;                   // 782
    const int MBp = ((MB64 + 7) / 8) * 8;              // 784

    // ---- GAT layer 1 (K=128, 8 column tiles) ----
    gemm_bf16_kernel<2, true, 8, 4><<<MBp * 8, 256, 0, stream>>>(
        xb, W1p, h1pre, as1, ad1, fAS, fAD, 8, NN, 128, 1024);
    gat_agg_fused_kernel<8, 4><<<NN, 256, 0, stream>>>(
        (const ushortT*)h1pre, fAS, fAD, b1, iRP, iES, (__hip_bfloat16*)bh1, NN);
    // ---- GAT layer 2 (K=1024, 4 column tiles) ----
    gemm_bf16_kernel<2, true, 4, 0><<<MBp * 4, 256, 0, stream>>>(
        bh1, W2p, h2pre, as2, ad2, fAS, fAD, 4, NN, 1024, 512);
    gat_agg_fused_kernel<4, 2><<<NN, 256, 0, stream>>>(
        (const ushortT*)h2pre, fAS, fAD, b2, iRP, iES, (__hip_bfloat16*)bh2, NN);
    // ---- GCN ----
    gemm_bf16_kernel<0, true, 1, 0><<<MBp, 256, 0, stream>>>(
        bh2, W3p, h3pre, nullptr, nullptr, nullptr, nullptr, 0, NN, 512, 128);
    gcn_agg_kernel<<<(NN + 1) / 2, 256, 0, stream>>>(
        (const ushortT*)h3pre, fDv, b3, iRP, iES, (__hip_bfloat16*)Qb, NN);
    // ---- fused 6-layer transformer ----
    transformer_fused_kernel<<<MB64, 256, 0, stream>>>(
        (const ushortT*)Qb, Wvop, bvo, wf1p, bf1, wf2p, bf2,
        ln1g, ln1b, ln2g, ln2b, fQ, NN);
    // ---- pool + head ----
    pool1_kernel<<<dim3(GG, 8), 128, 0, stream>>>(fQ, batch, psum, pmax, NN);
    pool2_kernel<<<GG, 128, 0, stream>>>(psum, pmax, batch, bn1g, bn1b, fHC, NN);
    head_kernel<<<GG, 64, 0, stream>>>(fHC, fc1w, fc1b, bn2g, bn2b, fc2w, fc2b, out);
}

// Round 10
// 1492.191 us; speedup vs baseline: 1.1721x; 1.1721x over previous
//
#include <hip/hip_runtime.h>
#include <hip/hip_bf16.h>
#include <math.h>

#define NN 50000
#define EE 200000
#define ET 250000   // EE + NN self loops
#define GG 64
#define LL 6

using short8 = __attribute__((ext_vector_type(8))) short;
using f32x4  = __attribute__((ext_vector_type(4))) float;
typedef unsigned short ushortT;

__device__ __forceinline__ float elu1(float x) { return x > 0.f ? x : expm1f(x); }
__device__ __forceinline__ float gelu_exact(float x) {
    return 0.5f * x * (1.f + erff(x * 0.70710678118654752440f));
}
__device__ __forceinline__ short f2bf(float f) {
    __hip_bfloat16 h = __float2bfloat16(f);
    return *reinterpret_cast<short*>(&h);
}
__device__ __forceinline__ float bf2f(ushortT u) {
    return __uint_as_float(((unsigned)u) << 16);
}

// ---------------- CSR build ----------------
__global__ void count_deg_kernel(const int* __restrict__ ei, int* __restrict__ deg) {
    int e = blockIdx.x * 256 + threadIdx.x;
    if (e >= ET) return;
    int dst = (e < EE) ? ei[EE + e] : (e - EE);
    atomicAdd(&deg[dst], 1);
}

__global__ void scan_kernel(const int* __restrict__ deg, int* __restrict__ row_ptr, int n) {
    __shared__ int s[1024];
    int tid = threadIdx.x;
    const int per = (n + 1023) / 1024;
    int lo = tid * per, hi = min(lo + per, n);
    int sum = 0;
    for (int i = lo; i < hi; i++) sum += deg[i];
    s[tid] = sum;
    __syncthreads();
    for (int off = 1; off < 1024; off <<= 1) {
        int t = (tid >= off) ? s[tid - off] : 0;
        __syncthreads();
        s[tid] += t;
        __syncthreads();
    }
    int run = s[tid] - sum;
    for (int i = lo; i < hi; i++) { row_ptr[i] = run; run += deg[i]; }
    if (tid == 1023) row_ptr[n] = s[1023];
}

__global__ void fill_csr_kernel(const int* __restrict__ ei, const int* __restrict__ row_ptr,
                                int* __restrict__ cursor, int* __restrict__ edge_src) {
    int e = blockIdx.x * 256 + threadIdx.x;
    if (e >= ET) return;
    int src, dst;
    if (e < EE) { src = ei[e]; dst = ei[EE + e]; }
    else        { src = e - EE; dst = e - EE; }
    int pos = atomicAdd(&cursor[dst], 1);
    edge_src[row_ptr[dst] + pos] = src;
}

__global__ void dinv_kernel(const int* __restrict__ row_ptr, float* __restrict__ dinv) {
    int n = blockIdx.x * 256 + threadIdx.x;
    if (n >= NN) return;
    int d = row_ptr[n + 1] - row_ptr[n];
    dinv[n] = (d > 0) ? rsqrtf((float)d) : 0.f;
}

// ---- fold wv into wo: Wvo = wv@wo, bvo = bv@wo + bo (fp32, exact) ----
__global__ void wvwo_kernel(const float* __restrict__ wv, const float* __restrict__ wo,
                            const float* __restrict__ bv, const float* __restrict__ bo,
                            float* __restrict__ Wvo, float* __restrict__ bvo) {
    int l = blockIdx.y;
    const float* Wv = wv + l * 16384;
    const float* Wo = wo + l * 16384;
    int tid = blockIdx.x * 256 + threadIdx.x;
    if (tid < 16384) {
        int r = tid >> 7, c = tid & 127;
        float s = 0.f;
        for (int k = 0; k < 128; k++) s += Wv[r * 128 + k] * Wo[k * 128 + c];
        Wvo[l * 16384 + tid] = s;
    }
    if (blockIdx.x == 0 && threadIdx.x < 128) {
        int c = threadIdx.x;
        float s = bo[l * 128 + c];
        for (int k = 0; k < 128; k++) s += bv[l * 128 + k] * Wo[k * 128 + c];
        bvo[l * 128 + c] = s;
    }
}

// ---- weight prep: fp32 [K,N] (ldb) -> bf16 MFMA B-fragment order ----
__global__ void bprep_kernel(const float* __restrict__ B, short* __restrict__ Bp,
                             int K, int N, int ldb, long srcStride) {
    int layer = blockIdx.y;
    const float* Bsrc = B + srcStride * layer;
    short* Bd = Bp + (size_t)K * N * layer;
    int total = (K >> 5) * (N >> 4) * 64;
    int tid = blockIdx.x * 256 + threadIdx.x;
    if (tid >= total) return;
    int l = tid & 63;
    int rest = tid >> 6;
    int kbc = K >> 5;
    int kb = rest % kbc;
    int c16 = rest / kbc;
    int n = c16 * 16 + (l & 15);
    int kbase = kb * 32 + (l >> 4) * 8;
    short v[8];
#pragma unroll
    for (int j = 0; j < 8; j++) v[j] = f2bf(Bsrc[(size_t)(kbase + j) * ldb + n]);
    *(uint4*)(Bd + (size_t)tid * 8) = *(uint4*)v;
}

__global__ void cast_bf16_kernel(const float* __restrict__ in, short* __restrict__ out, int n4) {
    int i = blockIdx.x * 256 + threadIdx.x;
    if (i >= n4) return;
    float4 v = *(const float4*)(in + (size_t)i * 4);
    short s[4] = { f2bf(v.x), f2bf(v.y), f2bf(v.z), f2bf(v.w) };
    *(uint2*)(out + (size_t)i * 4) = *(uint2*)s;
}

// ---------------- MFMA GEMM, LDS-free, XCD-aware column-fast split ----------
// 64-row blocks (16 rows/wave), RT=1 (VGPR ~48, high occupancy — R5/R8/R9
// showed multi-acc/row-tile variants lose more occupancy than they save).
// grid.x = NSPLIT * MBpad8. xcd = bx&7 (round-robin dispatch): all NSPLIT
// column tiles of one row band run on ONE XCD -> A band L2-resident there
// (R8: GAT2 FETCH 203->61 MB).
// EPI: 0 plain, 1 gelu, 2 asad + store, 3 residual(bf16)+LN in-place (Nc==128)
template <int EPI, bool BIAS, bool OUTBF16, int NSPLIT, int KBC>
__global__ __launch_bounds__(256) void gemm_bf16_kernel(
    const short* __restrict__ A, const short* __restrict__ Bp,
    const float* __restrict__ bias, void* __restrict__ Cv,
    const float* __restrict__ a_s, const float* __restrict__ a_d,
    float* __restrict__ as_out, float* __restrict__ ad_out, int asH,
    const ushortT* __restrict__ Rres, const float* __restrict__ lng,
    const float* __restrict__ lnb, float* __restrict__ Qout,
    __hip_bfloat16* __restrict__ Qbout,
    int M, int K, int Nc) {
    int t = threadIdx.x;
    int w = t >> 6, l = t & 63;
    int ln = l & 15, lq = l >> 4;
    int MBceil = (M + 63) >> 6;
    int bx = blockIdx.x;
    int xcd = bx & 7, idx = bx >> 3;
    int t2 = idx % NSPLIT;
    int mb = (idx / NSPLIT) * 8 + xcd;
    if (mb >= MBceil) return;
    int bm = mb * 64 + w * 16;
    int arow = bm + ln;
    bool aok = arow < M;
    int rowb = bm + lq * 4;
    const short* Ap = A + (size_t)arow * K + lq * 8;

    f32x4 acc[8];
#pragma unroll
    for (int j = 0; j < 8; j++) acc[j] = (f32x4){0.f, 0.f, 0.f, 0.f};

    if constexpr (KBC > 0) {
        short8 af[KBC];
#pragma unroll
        for (int kb = 0; kb < KBC; kb++)
            af[kb] = aok ? *(const short8*)(Ap + kb * 32) : (short8){0,0,0,0,0,0,0,0};
#pragma unroll
        for (int kb = 0; kb < KBC; kb++)
#pragma unroll
            for (int ct = 0; ct < 8; ct++) {
                short8 bfr = *(const short8*)(Bp + (((size_t)(t2 * 8 + ct) * KBC + kb) * 64 + l) * 8);
                acc[ct] = __builtin_amdgcn_mfma_f32_16x16x32_bf16(af[kb], bfr, acc[ct], 0, 0, 0);
            }
    } else {
        int kbc = K >> 5;
        for (int kb = 0; kb < kbc; kb++) {
            short8 af = aok ? *(const short8*)(Ap + kb * 32) : (short8){0,0,0,0,0,0,0,0};
#pragma unroll
            for (int ct = 0; ct < 8; ct++) {
                short8 bfr = *(const short8*)(Bp + (((size_t)(t2 * 8 + ct) * kbc + kb) * 64 + l) * 8);
                acc[ct] = __builtin_amdgcn_mfma_f32_16x16x32_bf16(af, bfr, acc[ct], 0, 0, 0);
            }
        }
    }

    if (EPI == 2) {
        const float* asv = a_s + t2 * 128;
        const float* adv = a_d + t2 * 128;
#pragma unroll
        for (int reg = 0; reg < 4; reg++) {
            float vs = 0.f, vd = 0.f;
#pragma unroll
            for (int ct = 0; ct < 8; ct++) {
                int colL = ct * 16 + ln;
                float av = acc[ct][reg];
                vs += av * asv[colL];
                vd += av * adv[colL];
            }
            vs += __shfl_xor(vs, 1); vs += __shfl_xor(vs, 2);
            vs += __shfl_xor(vs, 4); vs += __shfl_xor(vs, 8);
            vd += __shfl_xor(vd, 1); vd += __shfl_xor(vd, 2);
            vd += __shfl_xor(vd, 4); vd += __shfl_xor(vd, 8);
            int row = rowb + reg;
            if (ln == 0 && row < M) {
                as_out[(size_t)row * asH + t2] = vs;
                ad_out[(size_t)row * asH + t2] = vd;
            }
        }
    }
    if (EPI == 3) {
        // residual (bf16) + LayerNorm, Nc==128. Each row owned by one wave:
        // reads of the row precede its write in program order -> safe in-place.
        float v[8][4];
#pragma unroll
        for (int ct = 0; ct < 8; ct++) {
            int col = ct * 16 + ln;
            float bv_ = bias[col];
#pragma unroll
            for (int reg = 0; reg < 4; reg++) {
                int row = rowb + reg;
                float r = (row < M) ? bf2f(Rres[(size_t)row * 128 + col]) : 0.f;
                v[ct][reg] = acc[ct][reg] + bv_ + r;
            }
        }
#pragma unroll
        for (int reg = 0; reg < 4; reg++) {
            float s = 0.f;
#pragma unroll
            for (int ct = 0; ct < 8; ct++) s += v[ct][reg];
            s += __shfl_xor(s, 1); s += __shfl_xor(s, 2);
            s += __shfl_xor(s, 4); s += __shfl_xor(s, 8);
            float mean = s * (1.f / 128.f);
            float s2 = 0.f;
#pragma unroll
            for (int ct = 0; ct < 8; ct++) { float d = v[ct][reg] - mean; s2 += d * d; }
            s2 += __shfl_xor(s2, 1); s2 += __shfl_xor(s2, 2);
            s2 += __shfl_xor(s2, 4); s2 += __shfl_xor(s2, 8);
            float rstd = rsqrtf(s2 * (1.f / 128.f) + 1e-5f);
            int row = rowb + reg;
            if (row < M) {
#pragma unroll
                for (int ct = 0; ct < 8; ct++) {
                    int col = ct * 16 + ln;
                    float o = (v[ct][reg] - mean) * rstd * lng[col] + lnb[col];
                    Qbout[(size_t)row * 128 + col] = __float2bfloat16(o);
                    if (Qout) Qout[(size_t)row * 128 + col] = o;
                }
            }
        }
    }
    if (EPI == 0 || EPI == 1 || EPI == 2) {   // EPI2 also stores C
#pragma unroll
        for (int ct = 0; ct < 8; ct++) {
            int col = t2 * 128 + ct * 16 + ln;
            float bv_ = BIAS ? bias[col] : 0.f;
#pragma unroll
            for (int reg = 0; reg < 4; reg++) {
                int row = rowb + reg;
                if (row < M) {
                    float v = acc[ct][reg] + bv_;
                    if (EPI == 1) v = gelu_exact(v);
                    if (OUTBF16)
                        ((__hip_bfloat16*)Cv)[(size_t)row * Nc + col] = __float2bfloat16(v);
                    else
                        ((float*)Cv)[(size_t)row * Nc + col] = v;
                }
            }
        }
    }
}

// ---- fused multi-head GAT softmax-aggregate: one block per node ------------
template <int H, int CPT>
__global__ __launch_bounds__(256) void gat_agg_fused_kernel(
    const ushortT* __restrict__ hpre, const float* __restrict__ as_,
    const float* __restrict__ ad_, const float* __restrict__ bias,
    const int* __restrict__ row_ptr, const int* __restrict__ edge_src,
    __hip_bfloat16* __restrict__ out, int n_nodes) {
    int node = blockIdx.x;
    if (node >= n_nodes) return;
    int t = threadIdx.x;
    int c0 = t * CPT;
    int hb = c0 >> 7;
    int start = row_ptr[node];
    int deg = row_ptr[node + 1] - start;
    float adn = ad_[(size_t)node * H + hb];
    float m = -1e30f, S = 0.f;
    float acc[CPT];
#pragma unroll
    for (int c = 0; c < CPT; c++) acc[c] = 0.f;
    for (int j = 0; j < deg; j++) {
        int s = edge_src[start + j];
        float e = as_[(size_t)s * H + hb] + adn;
        e = e > 0.f ? e : 0.2f * e;
        float mn = fmaxf(m, e);
        float sc = expf(m - mn);
        float wj = expf(e - mn);
        S = S * sc + wj;
        const ushortT* hp = hpre + (size_t)s * (H * 128) + c0;
        float hv[CPT];
        if (CPT == 4) {
            uint2 u = *(const uint2*)hp;
            hv[0] = bf2f((ushortT)(u.x & 0xffff)); hv[1] = bf2f((ushortT)(u.x >> 16));
            hv[2] = bf2f((ushortT)(u.y & 0xffff)); hv[3] = bf2f((ushortT)(u.y >> 16));
        } else {
            unsigned u = *(const unsigned*)hp;
            hv[0] = bf2f((ushortT)(u & 0xffff)); hv[1] = bf2f((ushortT)(u >> 16));
        }
#pragma unroll
        for (int c = 0; c < CPT; c++) acc[c] = acc[c] * sc + wj * hv[c];
        m = mn;
    }
    float inv = 1.f / (S + 1e-16f);
#pragma unroll
    for (int c = 0; c < CPT; c++)
        out[(size_t)node * (H * 128) + c0 + c] =
            __float2bfloat16(elu1(acc[c] * inv + bias[c0 + c]));
}

// ---------------- GCN aggregation (bf16 in) -> bf16 Qb only -----------------
__global__ __launch_bounds__(256) void gcn_agg_kernel(
    const ushortT* __restrict__ hp, const float* __restrict__ dinv,
    const float* __restrict__ b3, const int* __restrict__ row_ptr,
    const int* __restrict__ edge_src,
    __hip_bfloat16* __restrict__ outb, int n_nodes) {
    int node = blockIdx.x * 2 + (threadIdx.x >> 7);
    int c = threadIdx.x & 127;
    if (node >= n_nodes) return;
    int start = row_ptr[node];
    int deg = row_ptr[node + 1] - start;
    float dn = dinv[node];
    float acc = 0.f;
    for (int j = 0; j < deg; j++) {
        int s = edge_src[start + j];
        acc += dinv[s] * dn * bf2f(hp[(size_t)s * 128 + c]);
    }
    outb[(size_t)node * 128 + c] = __float2bfloat16(elu1(acc + b3[c]));
}

// ---------------- pooling ----------------
__global__ void pool1_kernel(const float* __restrict__ Q, const int* __restrict__ batch,
                             float* __restrict__ psum, float* __restrict__ pmax, int n_nodes) {
    int g = blockIdx.x, seg = blockIdx.y;
    int c = threadIdx.x;
    int lo, hi;
    {
        int l = 0, h = n_nodes;
        while (l < h) { int mid = (l + h) >> 1; if (batch[mid] < g) l = mid + 1; else h = mid; }
        lo = l;
        l = lo; h = n_nodes;
        while (l < h) { int mid = (l + h) >> 1; if (batch[mid] < g + 1) l = mid + 1; else h = mid; }
        hi = l;
    }
    int len = hi - lo;
    int a = lo + (int)((long)len * seg / 8);
    int b = lo + (int)((long)len * (seg + 1) / 8);
    float s = 0.f, mx = -INFINITY;
    for (int n = a; n < b; n++) {
        float v = Q[(size_t)n * 128 + c];
        s += v;
        mx = fmaxf(mx, v);
    }
    psum[(g * 8 + seg) * 128 + c] = s;
    pmax[(g * 8 + seg) * 128 + c] = mx;
}

__global__ void pool2_kernel(const float* __restrict__ psum, const float* __restrict__ pmax,
                             const int* __restrict__ batch,
                             const float* __restrict__ bn1g, const float* __restrict__ bn1b,
                             float* __restrict__ hc, int n_nodes) {
    int g = blockIdx.x;
    int c = threadIdx.x;
    int lo, hi;
    {
        int l = 0, h = n_nodes;
        while (l < h) { int mid = (l + h) >> 1; if (batch[mid] < g) l = mid + 1; else h = mid; }
        lo = l;
        l = lo; h = n_nodes;
        while (l < h) { int mid = (l + h) >> 1; if (batch[mid] < g + 1) l = mid + 1; else h = mid; }
        hi = l;
    }
    int cnt = hi - lo;
    float s = 0.f, mx = -INFINITY;
    for (int seg = 0; seg < 8; seg++) {
        s += psum[(g * 8 + seg) * 128 + c];
        mx = fmaxf(mx, pmax[(g * 8 + seg) * 128 + c]);
    }
    float hm = s / fmaxf((float)cnt, 1.f);
    float hx = (cnt > 0 && isfinite(mx)) ? mx : 0.f;
    const float bn_s = 0.99999500003749968f;
    hc[g * 256 + c]       = hm * bn_s * bn1g[c] + bn1b[c];
    hc[g * 256 + 128 + c] = hx * bn_s * bn1g[128 + c] + bn1b[128 + c];
}

__global__ void head_kernel(const float* __restrict__ hc,
                            const float* __restrict__ fc1w, const float* __restrict__ fc1b,
                            const float* __restrict__ bn2g, const float* __restrict__ bn2b,
                            const float* __restrict__ fc2w, const float* __restrict__ fc2b,
                            float* __restrict__ out) {
    int g = blockIdx.x;
    int j = threadIdx.x;
    const float bn_s = 0.99999500003749968f;
    float acc = fc1b[j];
    for (int i = 0; i < 256; i++) acc += hc[g * 256 + i] * fc1w[i * 64 + j];
    acc = elu1(acc);
    acc = acc * bn_s * bn2g[j] + bn2b[j];
    __shared__ float sv[64];
    sv[j] = acc;
    __syncthreads();
    if (j < 2) {
        float o = fc2b[j];
        for (int i = 0; i < 64; i++) o += sv[i] * fc2w[i * 2 + j];
        out[g * 2 + j] = o;
    }
}

// ---------------- launch ----------------
extern "C" void kernel_launch(void* const* d_in, const int* in_sizes, int n_in,
                              void* d_out, int out_size, void* d_ws, size_t ws_size,
                              hipStream_t stream) {
    const float* x    = (const float*)d_in[0];
    const int*   ei   = (const int*)d_in[1];
    const int*   batch= (const int*)d_in[2];
    const float* W1   = (const float*)d_in[3];
    const float* as1  = (const float*)d_in[4];
    const float* ad1  = (const float*)d_in[5];
    const float* b1   = (const float*)d_in[6];
    const float* W2   = (const float*)d_in[7];
    const float* as2  = (const float*)d_in[8];
    const float* ad2  = (const float*)d_in[9];
    const float* b2   = (const float*)d_in[10];
    const float* W3   = (const float*)d_in[11];
    const float* b3   = (const float*)d_in[12];
    const float* wv   = (const float*)d_in[17];
    const float* bv   = (const float*)d_in[18];
    const float* wo   = (const float*)d_in[19];
    const float* bo   = (const float*)d_in[20];
    const float* ln1g = (const float*)d_in[21];
    const float* ln1b = (const float*)d_in[22];
    const float* ln2g = (const float*)d_in[23];
    const float* ln2b = (const float*)d_in[24];
    const float* wf1  = (const float*)d_in[25];
    const float* bf1  = (const float*)d_in[26];
    const float* wf2  = (const float*)d_in[27];
    const float* bf2  = (const float*)d_in[28];
    const float* bn1g = (const float*)d_in[29];
    const float* bn1b = (const float*)d_in[30];
    const float* fc1w = (const float*)d_in[31];
    const float* fc1b = (const float*)d_in[32];
    const float* bn2g = (const float*)d_in[33];
    const float* bn2b = (const float*)d_in[34];
    const float* fc2w = (const float*)d_in[35];
    const float* fc2b = (const float*)d_in[36];
    float* out = (float*)d_out;

    // ---- workspace layout (bytes), peak ~227 MB ----
    char* wsb = (char*)d_ws;
    short* xb    = (short*)wsb;                        // [N,128] bf16
    short* h1pre = (short*)(wsb + 12800000);           // [N,1024] bf16
    short* h2pre = (short*)(wsb + 12800000);           // [N,512] (h1pre dead)
    short* h3pre = (short*)(wsb + 12800000);           // [N,128] (h2pre dead)
    short* FFb   = (short*)(wsb + 25600000);           // [N,512] bf16 (transformer)
    short* bh1   = (short*)(wsb + 115200000);          // [N,1024] bf16
    short* bh2   = (short*)(wsb + 115200000);          // [N,512] (bh1 dead)
    float* fQ    = (float*)(wsb + 128000000);          // [N,128] fp32 (final state only)
    short* Qb    = (short*)(wsb + 153600000);          // [N,128] bf16 transformer state
    char* tail = wsb + 217600000;
    short* W1p  = (short*)tail;  tail += 262144;       // 128x1024
    short* W2p  = (short*)tail;  tail += 1048576;      // 1024x512
    short* W3p  = (short*)tail;  tail += 131072;       // 512x128
    short* Wvop = (short*)tail;  tail += 196608;       // 6 x 128x128
    short* wf1p = (short*)tail;  tail += 786432;       // 6 x 128x512
    short* wf2p = (short*)tail;  tail += 786432;       // 6 x 512x128
    float* Wvo  = (float*)tail;  tail += 393216;       // 6 x 128x128 fp32
    float* bvo  = (float*)tail;  tail += 3072;         // 6 x 128 fp32
    float* fAS  = (float*)tail;  tail += 1600000;      // [N,8]
    float* fAD  = (float*)tail;  tail += 1600000;      // [N,8]
    float* fDv  = (float*)tail;  tail += 200000;
    float* psum = (float*)tail;  tail += 262144;
    float* pmax = (float*)tail;  tail += 262144;
    float* fHC  = (float*)tail;  tail += 65536;
    int* iDeg   = (int*)tail;    tail += 200000;
    int* iRP    = (int*)tail;    tail += 200004;
    int* iCur   = (int*)tail;    tail += 200000;
    int* iES    = (int*)tail;    tail += 1000000;

    hipMemsetAsync(iDeg, 0, NN * sizeof(int), stream);
    hipMemsetAsync(iCur, 0, NN * sizeof(int), stream);

    count_deg_kernel<<<(ET + 255) / 256, 256, 0, stream>>>(ei, iDeg);
    scan_kernel<<<1, 1024, 0, stream>>>(iDeg, iRP, NN);
    fill_csr_kernel<<<(ET + 255) / 256, 256, 0, stream>>>(ei, iRP, iCur, iES);
    dinv_kernel<<<(NN + 255) / 256, 256, 0, stream>>>(iRP, fDv);

    wvwo_kernel<<<dim3(64, 6), 256, 0, stream>>>(wv, wo, bv, bo, Wvo, bvo);
    auto bprep = [&](const float* B, short* Bp, int K, int N, int ldb, long sStride, int layers) {
        int total = (K >> 5) * (N >> 4) * 64;
        dim3 grid((total + 255) / 256, layers);
        bprep_kernel<<<grid, 256, 0, stream>>>(B, Bp, K, N, ldb, sStride);
    };
    bprep(W1, W1p, 128, 1024, 1024, 0, 1);
    bprep(W2, W2p, 1024, 512, 512, 0, 1);
    bprep(W3, W3p, 512, 128, 128, 0, 1);
    bprep(Wvo, Wvop, 128, 128, 128, 16384, 6);
    bprep(wf1, wf1p, 128, 512, 512, 65536, 6);
    bprep(wf2, wf2p, 512, 128, 128, 65536, 6);
    cast_bf16_kernel<<<(NN * 128 / 4 + 255) / 256, 256, 0, stream>>>(x, xb, NN * 128 / 4);

    // 64-row blocks, padded to a multiple of 8 row-bands for the XCD swizzle
    const int MB64 = (NN + 63) / 64;                   // 782
    const int MBp = ((MB64 + 7) / 8) * 8;              // 784

    // ---- GAT layer 1 (K=128, 8 column tiles, XCD-local) ----
    gemm_bf16_kernel<2, false, true, 8, 4><<<MBp * 8, 256, 0, stream>>>(
        xb, W1p, nullptr, h1pre, as1, ad1, fAS, fAD, 8,
        nullptr, nullptr, nullptr, nullptr, nullptr, NN, 128, 1024);
    gat_agg_fused_kernel<8, 4><<<NN, 256, 0, stream>>>(
        (const ushortT*)h1pre, fAS, fAD, b1, iRP, iES, (__hip_bfloat16*)bh1, NN);
    // ---- GAT layer 2 (K=1024, 4 column tiles, XCD-local) ----
    gemm_bf16_kernel<2, false, true, 4, 0><<<MBp * 4, 256, 0, stream>>>(
        bh1, W2p, nullptr, h2pre, as2, ad2, fAS, fAD, 4,
        nullptr, nullptr, nullptr, nullptr, nullptr, NN, 1024, 512);
    gat_agg_fused_kernel<4, 2><<<NN, 256, 0, stream>>>(
        (const ushortT*)h2pre, fAS, fAD, b2, iRP, iES, (__hip_bfloat16*)bh2, NN);
    // ---- GCN ----
    gemm_bf16_kernel<0, false, true, 1, 0><<<MBp, 256, 0, stream>>>(
        bh2, W3p, nullptr, h3pre, nullptr, nullptr, nullptr, nullptr, 0,
        nullptr, nullptr, nullptr, nullptr, nullptr, NN, 512, 128);
    gcn_agg_kernel<<<(NN + 1) / 2, 256, 0, stream>>>(
        (const ushortT*)h3pre, fDv, b3, iRP, iES, (__hip_bfloat16*)Qb, NN);
    // ---- Transformer (seq_len=1; attn folded; bf16 residual state in Qb) ----
    for (int l = 0; l < LL; l++) {
        gemm_bf16_kernel<3, true, false, 1, 4><<<MBp, 256, 0, stream>>>(
            Qb, Wvop + l * 16384, bvo + l * 128, nullptr, nullptr, nullptr, nullptr, nullptr, 0,
            (const ushortT*)Qb, ln1g + l * 128, ln1b + l * 128, nullptr, (__hip_bfloat16*)Qb,
            NN, 128, 128);
        gemm_bf16_kernel<1, true, true, 4, 4><<<MBp * 4, 256, 0, stream>>>(
            Qb, wf1p + l * 65536, bf1 + l * 512, FFb, nullptr, nullptr, nullptr, nullptr, 0,
            nullptr, nullptr, nullptr, nullptr, nullptr, NN, 128, 512);
        gemm_bf16_kernel<3, true, false, 1, 0><<<MBp, 256, 0, stream>>>(
            FFb, wf2p + l * 65536, bf2 + l * 128, nullptr, nullptr, nullptr, nullptr, nullptr, 0,
            (const ushortT*)Qb, ln2g + l * 128, ln2b + l * 128,
            (l == LL - 1) ? fQ : nullptr, (__hip_bfloat16*)Qb, NN, 512, 128);
    }
    // ---- pool + head ----
    pool1_kernel<<<dim3(GG, 8), 128, 0, stream>>>(fQ, batch, psum, pmax, NN);
    pool2_kernel<<<GG, 128, 0, stream>>>(psum, pmax, batch, bn1g, bn1b, fHC, NN);
    head_kernel<<<GG, 64, 0, stream>>>(fHC, fc1w, fc1b, bn2g, bn2b, fc2w, fc2b, out);
}

// Round 11
// 1335.499 us; speedup vs baseline: 1.3097x; 1.1173x over previous
//
#include <hip/hip_runtime.h>
#include <hip/hip_bf16.h>
#include <math.h>

#define NN 50000
#define EE 200000
#define ET 250000   // EE + NN self loops
#define GG 64
#define LL 6

using short8 = __attribute__((ext_vector_type(8))) short;
using f32x4  = __attribute__((ext_vector_type(4))) float;
typedef unsigned short ushortT;

__device__ __forceinline__ float elu1(float x) { return x > 0.f ? x : expm1f(x); }
__device__ __forceinline__ float gelu_exact(float x) {
    return 0.5f * x * (1.f + erff(x * 0.70710678118654752440f));
}
__device__ __forceinline__ short f2bf(float f) {
    __hip_bfloat16 h = __float2bfloat16(f);
    return *reinterpret_cast<short*>(&h);
}
__device__ __forceinline__ float bf2f(ushortT u) {
    return __uint_as_float(((unsigned)u) << 16);
}

// ---------------- CSR build ----------------
__global__ void count_deg_kernel(const int* __restrict__ ei, int* __restrict__ deg) {
    int e = blockIdx.x * 256 + threadIdx.x;
    if (e >= ET) return;
    int dst = (e < EE) ? ei[EE + e] : (e - EE);
    atomicAdd(&deg[dst], 1);
}

__global__ void scan_kernel(const int* __restrict__ deg, int* __restrict__ row_ptr, int n) {
    __shared__ int s[1024];
    int tid = threadIdx.x;
    const int per = (n + 1023) / 1024;
    int lo = tid * per, hi = min(lo + per, n);
    int sum = 0;
    for (int i = lo; i < hi; i++) sum += deg[i];
    s[tid] = sum;
    __syncthreads();
    for (int off = 1; off < 1024; off <<= 1) {
        int t = (tid >= off) ? s[tid - off] : 0;
        __syncthreads();
        s[tid] += t;
        __syncthreads();
    }
    int run = s[tid] - sum;
    for (int i = lo; i < hi; i++) { row_ptr[i] = run; run += deg[i]; }
    if (tid == 1023) row_ptr[n] = s[1023];
}

__global__ void fill_csr_kernel(const int* __restrict__ ei, const int* __restrict__ row_ptr,
                                int* __restrict__ cursor, int* __restrict__ edge_src) {
    int e = blockIdx.x * 256 + threadIdx.x;
    if (e >= ET) return;
    int src, dst;
    if (e < EE) { src = ei[e]; dst = ei[EE + e]; }
    else        { src = e - EE; dst = e - EE; }
    int pos = atomicAdd(&cursor[dst], 1);
    edge_src[row_ptr[dst] + pos] = src;
}

__global__ void dinv_kernel(const int* __restrict__ row_ptr, float* __restrict__ dinv) {
    int n = blockIdx.x * 256 + threadIdx.x;
    if (n >= NN) return;
    int d = row_ptr[n + 1] - row_ptr[n];
    dinv[n] = (d > 0) ? rsqrtf((float)d) : 0.f;
}

// ---- fold wv into wo: Wvo = wv@wo, bvo = bv@wo + bo (fp32, exact) ----
__global__ void wvwo_kernel(const float* __restrict__ wv, const float* __restrict__ wo,
                            const float* __restrict__ bv, const float* __restrict__ bo,
                            float* __restrict__ Wvo, float* __restrict__ bvo) {
    int l = blockIdx.y;
    const float* Wv = wv + l * 16384;
    const float* Wo = wo + l * 16384;
    int tid = blockIdx.x * 256 + threadIdx.x;
    if (tid < 16384) {
        int r = tid >> 7, c = tid & 127;
        float s = 0.f;
        for (int k = 0; k < 128; k++) s += Wv[r * 128 + k] * Wo[k * 128 + c];
        Wvo[l * 16384 + tid] = s;
    }
    if (blockIdx.x == 0 && threadIdx.x < 128) {
        int c = threadIdx.x;
        float s = bo[l * 128 + c];
        for (int k = 0; k < 128; k++) s += bv[l * 128 + k] * Wo[k * 128 + c];
        bvo[l * 128 + c] = s;
    }
}

// ---- weight prep: fp32 [K,N] (ldb) -> bf16 MFMA B-fragment order ----
__global__ void bprep_kernel(const float* __restrict__ B, short* __restrict__ Bp,
                             int K, int N, int ldb, long srcStride) {
    int layer = blockIdx.y;
    const float* Bsrc = B + srcStride * layer;
    short* Bd = Bp + (size_t)K * N * layer;
    int total = (K >> 5) * (N >> 4) * 64;
    int tid = blockIdx.x * 256 + threadIdx.x;
    if (tid >= total) return;
    int l = tid & 63;
    int rest = tid >> 6;
    int kbc = K >> 5;
    int kb = rest % kbc;
    int c16 = rest / kbc;
    int n = c16 * 16 + (l & 15);
    int kbase = kb * 32 + (l >> 4) * 8;
    short v[8];
#pragma unroll
    for (int j = 0; j < 8; j++) v[j] = f2bf(Bsrc[(size_t)(kbase + j) * ldb + n]);
    *(uint4*)(Bd + (size_t)tid * 8) = *(uint4*)v;
}

__global__ void cast_bf16_kernel(const float* __restrict__ in, short* __restrict__ out, int n4) {
    int i = blockIdx.x * 256 + threadIdx.x;
    if (i >= n4) return;
    float4 v = *(const float4*)(in + (size_t)i * 4);
    short s[4] = { f2bf(v.x), f2bf(v.y), f2bf(v.z), f2bf(v.w) };
    *(uint2*)(out + (size_t)i * 4) = *(uint2*)s;
}

// ---------------- MFMA GEMM, LDS B-staging, XCD-aware column-fast split -----
// 64-row blocks (16 rows/wave), RT=1 (VGPR ~48-56: occupancy rules, per
// R5/R8/R9). grid.x = NSPLIT * MBpad8; xcd = bx&7 keeps one row band's NSPLIT
// column tiles on one XCD (R8: GAT2 FETCH 203->61 MB).
// B fragments staged in LDS (contiguous uint4 both ways -> conflict-free):
//   KBC>0 : whole 8*KBC KB tile staged once, ONE barrier total.
//   KBC==0: 8 KB per-kb slice, double-buffered, one barrier per kb.
// EPI: 0 plain, 1 gelu, 2 asad + store, 3 residual(bf16)+LN in-place (Nc==128)
template <int EPI, bool BIAS, bool OUTBF16, int NSPLIT, int KBC>
__global__ __launch_bounds__(256) void gemm_bf16_kernel(
    const short* __restrict__ A, const short* __restrict__ Bp,
    const float* __restrict__ bias, void* __restrict__ Cv,
    const float* __restrict__ a_s, const float* __restrict__ a_d,
    float* __restrict__ as_out, float* __restrict__ ad_out, int asH,
    const ushortT* __restrict__ Rres, const float* __restrict__ lng,
    const float* __restrict__ lnb, float* __restrict__ Qout,
    __hip_bfloat16* __restrict__ Qbout,
    int M, int K, int Nc) {
    __shared__ short Bs[(KBC > 0) ? KBC * 4096 : 8192];
    int t = threadIdx.x;
    int w = t >> 6, l = t & 63;
    int ln = l & 15, lq = l >> 4;
    int MBceil = (M + 63) >> 6;
    int bx = blockIdx.x;
    int xcd = bx & 7, idx = bx >> 3;
    int t2 = idx % NSPLIT;
    int mb = (idx / NSPLIT) * 8 + xcd;
    if (mb >= MBceil) return;
    int bm = mb * 64 + w * 16;
    int arow = bm + ln;
    bool aok = arow < M;
    int rowb = bm + lq * 4;
    const short* Ap = A + (size_t)arow * K + lq * 8;

    f32x4 acc[8];
#pragma unroll
    for (int j = 0; j < 8; j++) acc[j] = (f32x4){0.f, 0.f, 0.f, 0.f};

    if constexpr (KBC > 0) {
        // stage whole B tile (contiguous chunk: 8*KBC fragments)
        {
            const uint4* src = (const uint4*)(Bp + (size_t)t2 * KBC * 4096);
            uint4* dst = (uint4*)Bs;
#pragma unroll
            for (int i = 0; i < KBC * 2; i++)
                dst[i * 256 + t] = src[i * 256 + t];
        }
        short8 af[KBC];
#pragma unroll
        for (int kb = 0; kb < KBC; kb++)
            af[kb] = aok ? *(const short8*)(Ap + kb * 32) : (short8){0,0,0,0,0,0,0,0};
        __syncthreads();
#pragma unroll
        for (int kb = 0; kb < KBC; kb++)
#pragma unroll
            for (int ct = 0; ct < 8; ct++) {
                short8 bfr = *(const short8*)(Bs + ((ct * KBC + kb) * 64 + l) * 8);
                acc[ct] = __builtin_amdgcn_mfma_f32_16x16x32_bf16(af[kb], bfr, acc[ct], 0, 0, 0);
            }
    } else {
        int kbc = K >> 5;
        int sct = t >> 5, spart = t & 31;   // staging role: fragment, quarter
        auto stage = [&](int buf, int kb) {
            const uint4* src = (const uint4*)(Bp + ((size_t)(t2 * 8 + sct) * kbc + kb) * 512);
            uint4* dst = (uint4*)(Bs + buf * 4096 + sct * 512);
            dst[spart * 2]     = src[spart * 2];
            dst[spart * 2 + 1] = src[spart * 2 + 1];
        };
        stage(0, 0);
        __syncthreads();
        for (int kb = 0; kb < kbc; kb++) {
            if (kb + 1 < kbc) stage((kb + 1) & 1, kb + 1);
            short8 af = aok ? *(const short8*)(Ap + kb * 32) : (short8){0,0,0,0,0,0,0,0};
            const short* bsb = Bs + (kb & 1) * 4096;
#pragma unroll
            for (int ct = 0; ct < 8; ct++) {
                short8 bfr = *(const short8*)(bsb + (ct * 64 + l) * 8);
                acc[ct] = __builtin_amdgcn_mfma_f32_16x16x32_bf16(af, bfr, acc[ct], 0, 0, 0);
            }
            __syncthreads();
        }
    }

    if (EPI == 2) {
        const float* asv = a_s + t2 * 128;
        const float* adv = a_d + t2 * 128;
#pragma unroll
        for (int reg = 0; reg < 4; reg++) {
            float vs = 0.f, vd = 0.f;
#pragma unroll
            for (int ct = 0; ct < 8; ct++) {
                int colL = ct * 16 + ln;
                float av = acc[ct][reg];
                vs += av * asv[colL];
                vd += av * adv[colL];
            }
            vs += __shfl_xor(vs, 1); vs += __shfl_xor(vs, 2);
            vs += __shfl_xor(vs, 4); vs += __shfl_xor(vs, 8);
            vd += __shfl_xor(vd, 1); vd += __shfl_xor(vd, 2);
            vd += __shfl_xor(vd, 4); vd += __shfl_xor(vd, 8);
            int row = rowb + reg;
            if (ln == 0 && row < M) {
                as_out[(size_t)row * asH + t2] = vs;
                ad_out[(size_t)row * asH + t2] = vd;
            }
        }
    }
    if (EPI == 3) {
        // residual (bf16) + LayerNorm, Nc==128. Each row owned by one wave:
        // reads of the row precede its write in program order -> safe in-place.
        float v[8][4];
#pragma unroll
        for (int ct = 0; ct < 8; ct++) {
            int col = ct * 16 + ln;
            float bv_ = bias[col];
#pragma unroll
            for (int reg = 0; reg < 4; reg++) {
                int row = rowb + reg;
                float r = (row < M) ? bf2f(Rres[(size_t)row * 128 + col]) : 0.f;
                v[ct][reg] = acc[ct][reg] + bv_ + r;
            }
        }
#pragma unroll
        for (int reg = 0; reg < 4; reg++) {
            float s = 0.f;
#pragma unroll
            for (int ct = 0; ct < 8; ct++) s += v[ct][reg];
            s += __shfl_xor(s, 1); s += __shfl_xor(s, 2);
            s += __shfl_xor(s, 4); s += __shfl_xor(s, 8);
            float mean = s * (1.f / 128.f);
            float s2 = 0.f;
#pragma unroll
            for (int ct = 0; ct < 8; ct++) { float d = v[ct][reg] - mean; s2 += d * d; }
            s2 += __shfl_xor(s2, 1); s2 += __shfl_xor(s2, 2);
            s2 += __shfl_xor(s2, 4); s2 += __shfl_xor(s2, 8);
            float rstd = rsqrtf(s2 * (1.f / 128.f) + 1e-5f);
            int row = rowb + reg;
            if (row < M) {
#pragma unroll
                for (int ct = 0; ct < 8; ct++) {
                    int col = ct * 16 + ln;
                    float o = (v[ct][reg] - mean) * rstd * lng[col] + lnb[col];
                    Qbout[(size_t)row * 128 + col] = __float2bfloat16(o);
                    if (Qout) Qout[(size_t)row * 128 + col] = o;
                }
            }
        }
    }
    if (EPI == 0 || EPI == 1 || EPI == 2) {   // EPI2 also stores C
#pragma unroll
        for (int ct = 0; ct < 8; ct++) {
            int col = t2 * 128 + ct * 16 + ln;
            float bv_ = BIAS ? bias[col] : 0.f;
#pragma unroll
            for (int reg = 0; reg < 4; reg++) {
                int row = rowb + reg;
                if (row < M) {
                    float v = acc[ct][reg] + bv_;
                    if (EPI == 1) v = gelu_exact(v);
                    if (OUTBF16)
                        ((__hip_bfloat16*)Cv)[(size_t)row * Nc + col] = __float2bfloat16(v);
                    else
                        ((float*)Cv)[(size_t)row * Nc + col] = v;
                }
            }
        }
    }
}

// ---- fused multi-head GAT softmax-aggregate: 2 nodes/block, 128 thr/node ---
// CPT == H (so 128 threads cover H*128 cols): H=8 -> uint4 gathers (16B/lane),
// H=4 -> uint2. No barriers (per-thread serial edge walk).
template <int H>
__global__ __launch_bounds__(256) void gat_agg_fused_kernel(
    const ushortT* __restrict__ hpre, const float* __restrict__ as_,
    const float* __restrict__ ad_, const float* __restrict__ bias,
    const int* __restrict__ row_ptr, const int* __restrict__ edge_src,
    __hip_bfloat16* __restrict__ out, int n_nodes) {
    const int CPT = H;
    int node = blockIdx.x * 2 + (threadIdx.x >> 7);
    if (node >= n_nodes) return;
    int tt = threadIdx.x & 127;
    int c0 = tt * CPT;
    int hb = c0 >> 7;
    int start = row_ptr[node];
    int deg = row_ptr[node + 1] - start;
    float adn = ad_[(size_t)node * H + hb];
    float m = -1e30f, S = 0.f;
    float acc[CPT];
#pragma unroll
    for (int c = 0; c < CPT; c++) acc[c] = 0.f;
    for (int j = 0; j < deg; j++) {
        int s = edge_src[start + j];
        float e = as_[(size_t)s * H + hb] + adn;
        e = e > 0.f ? e : 0.2f * e;
        float mn = fmaxf(m, e);
        float sc = expf(m - mn);
        float wj = expf(e - mn);
        S = S * sc + wj;
        const ushortT* hp = hpre + (size_t)s * (H * 128) + c0;
        float hv[CPT];
        if (CPT == 8) {
            uint4 u = *(const uint4*)hp;
            hv[0] = bf2f((ushortT)(u.x & 0xffff)); hv[1] = bf2f((ushortT)(u.x >> 16));
            hv[2] = bf2f((ushortT)(u.y & 0xffff)); hv[3] = bf2f((ushortT)(u.y >> 16));
            hv[4] = bf2f((ushortT)(u.z & 0xffff)); hv[5] = bf2f((ushortT)(u.z >> 16));
            hv[6] = bf2f((ushortT)(u.w & 0xffff)); hv[7] = bf2f((ushortT)(u.w >> 16));
        } else {
            uint2 u = *(const uint2*)hp;
            hv[0] = bf2f((ushortT)(u.x & 0xffff)); hv[1] = bf2f((ushortT)(u.x >> 16));
            hv[2] = bf2f((ushortT)(u.y & 0xffff)); hv[3] = bf2f((ushortT)(u.y >> 16));
        }
#pragma unroll
        for (int c = 0; c < CPT; c++) acc[c] = acc[c] * sc + wj * hv[c];
        m = mn;
    }
    float inv = 1.f / (S + 1e-16f);
#pragma unroll
    for (int c = 0; c < CPT; c++)
        out[(size_t)node * (H * 128) + c0 + c] =
            __float2bfloat16(elu1(acc[c] * inv + bias[c0 + c]));
}

// ---------------- GCN aggregation (bf16 in) -> bf16 Qb only -----------------
__global__ __launch_bounds__(256) void gcn_agg_kernel(
    const ushortT* __restrict__ hp, const float* __restrict__ dinv,
    const float* __restrict__ b3, const int* __restrict__ row_ptr,
    const int* __restrict__ edge_src,
    __hip_bfloat16* __restrict__ outb, int n_nodes) {
    int node = blockIdx.x * 2 + (threadIdx.x >> 7);
    int c = threadIdx.x & 127;
    if (node >= n_nodes) return;
    int start = row_ptr[node];
    int deg = row_ptr[node + 1] - start;
    float dn = dinv[node];
    float acc = 0.f;
    for (int j = 0; j < deg; j++) {
        int s = edge_src[start + j];
        acc += dinv[s] * dn * bf2f(hp[(size_t)s * 128 + c]);
    }
    outb[(size_t)node * 128 + c] = __float2bfloat16(elu1(acc + b3[c]));
}

// ---------------- pooling ----------------
__global__ void pool1_kernel(const float* __restrict__ Q, const int* __restrict__ batch,
                             float* __restrict__ psum, float* __restrict__ pmax, int n_nodes) {
    int g = blockIdx.x, seg = blockIdx.y;
    int c = threadIdx.x;
    int lo, hi;
    {
        int l = 0, h = n_nodes;
        while (l < h) { int mid = (l + h) >> 1; if (batch[mid] < g) l = mid + 1; else h = mid; }
        lo = l;
        l = lo; h = n_nodes;
        while (l < h) { int mid = (l + h) >> 1; if (batch[mid] < g + 1) l = mid + 1; else h = mid; }
        hi = l;
    }
    int len = hi - lo;
    int a = lo + (int)((long)len * seg / 8);
    int b = lo + (int)((long)len * (seg + 1) / 8);
    float s = 0.f, mx = -INFINITY;
    for (int n = a; n < b; n++) {
        float v = Q[(size_t)n * 128 + c];
        s += v;
        mx = fmaxf(mx, v);
    }
    psum[(g * 8 + seg) * 128 + c] = s;
    pmax[(g * 8 + seg) * 128 + c] = mx;
}

__global__ void pool2_kernel(const float* __restrict__ psum, const float* __restrict__ pmax,
                             const int* __restrict__ batch,
                             const float* __restrict__ bn1g, const float* __restrict__ bn1b,
                             float* __restrict__ hc, int n_nodes) {
    int g = blockIdx.x;
    int c = threadIdx.x;
    int lo, hi;
    {
        int l = 0, h = n_nodes;
        while (l < h) { int mid = (l + h) >> 1; if (batch[mid] < g) l = mid + 1; else h = mid; }
        lo = l;
        l = lo; h = n_nodes;
        while (l < h) { int mid = (l + h) >> 1; if (batch[mid] < g + 1) l = mid + 1; else h = mid; }
        hi = l;
    }
    int cnt = hi - lo;
    float s = 0.f, mx = -INFINITY;
    for (int seg = 0; seg < 8; seg++) {
        s += psum[(g * 8 + seg) * 128 + c];
        mx = fmaxf(mx, pmax[(g * 8 + seg) * 128 + c]);
    }
    float hm = s / fmaxf((float)cnt, 1.f);
    float hx = (cnt > 0 && isfinite(mx)) ? mx : 0.f;
    const float bn_s = 0.99999500003749968f;
    hc[g * 256 + c]       = hm * bn_s * bn1g[c] + bn1b[c];
    hc[g * 256 + 128 + c] = hx * bn_s * bn1g[128 + c] + bn1b[128 + c];
}

__global__ void head_kernel(const float* __restrict__ hc,
                            const float* __restrict__ fc1w, const float* __restrict__ fc1b,
                            const float* __restrict__ bn2g, const float* __restrict__ bn2b,
                            const float* __restrict__ fc2w, const float* __restrict__ fc2b,
                            float* __restrict__ out) {
    int g = blockIdx.x;
    int j = threadIdx.x;
    const float bn_s = 0.99999500003749968f;
    float acc = fc1b[j];
    for (int i = 0; i < 256; i++) acc += hc[g * 256 + i] * fc1w[i * 64 + j];
    acc = elu1(acc);
    acc = acc * bn_s * bn2g[j] + bn2b[j];
    __shared__ float sv[64];
    sv[j] = acc;
    __syncthreads();
    if (j < 2) {
        float o = fc2b[j];
        for (int i = 0; i < 64; i++) o += sv[i] * fc2w[i * 2 + j];
        out[g * 2 + j] = o;
    }
}

// ---------------- launch ----------------
extern "C" void kernel_launch(void* const* d_in, const int* in_sizes, int n_in,
                              void* d_out, int out_size, void* d_ws, size_t ws_size,
                              hipStream_t stream) {
    const float* x    = (const float*)d_in[0];
    const int*   ei   = (const int*)d_in[1];
    const int*   batch= (const int*)d_in[2];
    const float* W1   = (const float*)d_in[3];
    const float* as1  = (const float*)d_in[4];
    const float* ad1  = (const float*)d_in[5];
    const float* b1   = (const float*)d_in[6];
    const float* W2   = (const float*)d_in[7];
    const float* as2  = (const float*)d_in[8];
    const float* ad2  = (const float*)d_in[9];
    const float* b2   = (const float*)d_in[10];
    const float* W3   = (const float*)d_in[11];
    const float* b3   = (const float*)d_in[12];
    const float* wv   = (const float*)d_in[17];
    const float* bv   = (const float*)d_in[18];
    const float* wo   = (const float*)d_in[19];
    const float* bo   = (const float*)d_in[20];
    const float* ln1g = (const float*)d_in[21];
    const float* ln1b = (const float*)d_in[22];
    const float* ln2g = (const float*)d_in[23];
    const float* ln2b = (const float*)d_in[24];
    const float* wf1  = (const float*)d_in[25];
    const float* bf1  = (const float*)d_in[26];
    const float* wf2  = (const float*)d_in[27];
    const float* bf2  = (const float*)d_in[28];
    const float* bn1g = (const float*)d_in[29];
    const float* bn1b = (const float*)d_in[30];
    const float* fc1w = (const float*)d_in[31];
    const float* fc1b = (const float*)d_in[32];
    const float* bn2g = (const float*)d_in[33];
    const float* bn2b = (const float*)d_in[34];
    const float* fc2w = (const float*)d_in[35];
    const float* fc2b = (const float*)d_in[36];
    float* out = (float*)d_out;

    // ---- workspace layout (bytes), peak ~227 MB ----
    char* wsb = (char*)d_ws;
    short* xb    = (short*)wsb;                        // [N,128] bf16
    short* h1pre = (short*)(wsb + 12800000);           // [N,1024] bf16
    short* h2pre = (short*)(wsb + 12800000);           // [N,512] (h1pre dead)
    short* h3pre = (short*)(wsb + 12800000);           // [N,128] (h2pre dead)
    short* FFb   = (short*)(wsb + 25600000);           // [N,512] bf16 (transformer)
    short* bh1   = (short*)(wsb + 115200000);          // [N,1024] bf16
    short* bh2   = (short*)(wsb + 115200000);          // [N,512] (bh1 dead)
    float* fQ    = (float*)(wsb + 128000000);          // [N,128] fp32 (final state only)
    short* Qb    = (short*)(wsb + 153600000);          // [N,128] bf16 transformer state
    char* tail = wsb + 217600000;
    short* W1p  = (short*)tail;  tail += 262144;       // 128x1024
    short* W2p  = (short*)tail;  tail += 1048576;      // 1024x512
    short* W3p  = (short*)tail;  tail += 131072;       // 512x128
    short* Wvop = (short*)tail;  tail += 196608;       // 6 x 128x128
    short* wf1p = (short*)tail;  tail += 786432;       // 6 x 128x512
    short* wf2p = (short*)tail;  tail += 786432;       // 6 x 512x128
    float* Wvo  = (float*)tail;  tail += 393216;       // 6 x 128x128 fp32
    float* bvo  = (float*)tail;  tail += 3072;         // 6 x 128 fp32
    float* fAS  = (float*)tail;  tail += 1600000;      // [N,8]
    float* fAD  = (float*)tail;  tail += 1600000;      // [N,8]
    float* fDv  = (float*)tail;  tail += 200000;
    float* psum = (float*)tail;  tail += 262144;
    float* pmax = (float*)tail;  tail += 262144;
    float* fHC  = (float*)tail;  tail += 65536;
    int* iDeg   = (int*)tail;    tail += 200000;
    int* iRP    = (int*)tail;    tail += 200004;
    int* iCur   = (int*)tail;    tail += 200000;
    int* iES    = (int*)tail;    tail += 1000000;

    hipMemsetAsync(iDeg, 0, NN * sizeof(int), stream);
    hipMemsetAsync(iCur, 0, NN * sizeof(int), stream);

    count_deg_kernel<<<(ET + 255) / 256, 256, 0, stream>>>(ei, iDeg);
    scan_kernel<<<1, 1024, 0, stream>>>(iDeg, iRP, NN);
    fill_csr_kernel<<<(ET + 255) / 256, 256, 0, stream>>>(ei, iRP, iCur, iES);
    dinv_kernel<<<(NN + 255) / 256, 256, 0, stream>>>(iRP, fDv);

    wvwo_kernel<<<dim3(64, 6), 256, 0, stream>>>(wv, wo, bv, bo, Wvo, bvo);
    auto bprep = [&](const float* B, short* Bp, int K, int N, int ldb, long sStride, int layers) {
        int total = (K >> 5) * (N >> 4) * 64;
        dim3 grid((total + 255) / 256, layers);
        bprep_kernel<<<grid, 256, 0, stream>>>(B, Bp, K, N, ldb, sStride);
    };
    bprep(W1, W1p, 128, 1024, 1024, 0, 1);
    bprep(W2, W2p, 1024, 512, 512, 0, 1);
    bprep(W3, W3p, 512, 128, 128, 0, 1);
    bprep(Wvo, Wvop, 128, 128, 128, 16384, 6);
    bprep(wf1, wf1p, 128, 512, 512, 65536, 6);
    bprep(wf2, wf2p, 512, 128, 128, 65536, 6);
    cast_bf16_kernel<<<(NN * 128 / 4 + 255) / 256, 256, 0, stream>>>(x, xb, NN * 128 / 4);

    // 64-row blocks, padded to a multiple of 8 row-bands for the XCD swizzle
    const int MB64 = (NN + 63) / 64;                   // 782
    const int MBp = ((MB64 + 7) / 8) * 8;              // 784

    // ---- GAT layer 1 (K=128, 8 column tiles, XCD-local, LDS-B) ----
    gemm_bf16_kernel<2, false, true, 8, 4><<<MBp * 8, 256, 0, stream>>>(
        xb, W1p, nullptr, h1pre, as1, ad1, fAS, fAD, 8,
        nullptr, nullptr, nullptr, nullptr, nullptr, NN, 128, 1024);
    gat_agg_fused_kernel<8><<<(NN + 1) / 2, 256, 0, stream>>>(
        (const ushortT*)h1pre, fAS, fAD, b1, iRP, iES, (__hip_bfloat16*)bh1, NN);
    // ---- GAT layer 2 (K=1024, 4 column tiles, XCD-local, LDS-B dbuf) ----
    gemm_bf16_kernel<2, false, true, 4, 0><<<MBp * 4, 256, 0, stream>>>(
        bh1, W2p, nullptr, h2pre, as2, ad2, fAS, fAD, 4,
        nullptr, nullptr, nullptr, nullptr, nullptr, NN, 1024, 512);
    gat_agg_fused_kernel<4><<<(NN + 1) / 2, 256, 0, stream>>>(
        (const ushortT*)h2pre, fAS, fAD, b2, iRP, iES, (__hip_bfloat16*)bh2, NN);
    // ---- GCN ----
    gemm_bf16_kernel<0, false, true, 1, 0><<<MBp, 256, 0, stream>>>(
        bh2, W3p, nullptr, h3pre, nullptr, nullptr, nullptr, nullptr, 0,
        nullptr, nullptr, nullptr, nullptr, nullptr, NN, 512, 128);
    gcn_agg_kernel<<<(NN + 1) / 2, 256, 0, stream>>>(
        (const ushortT*)h3pre, fDv, b3, iRP, iES, (__hip_bfloat16*)Qb, NN);
    // ---- Transformer (seq_len=1; attn folded; bf16 residual state in Qb) ----
    for (int l = 0; l < LL; l++) {
        gemm_bf16_kernel<3, true, false, 1, 4><<<MBp, 256, 0, stream>>>(
            Qb, Wvop + l * 16384, bvo + l * 128, nullptr, nullptr, nullptr, nullptr, nullptr, 0,
            (const ushortT*)Qb, ln1g + l * 128, ln1b + l * 128, nullptr, (__hip_bfloat16*)Qb,
            NN, 128, 128);
        gemm_bf16_kernel<1, true, true, 4, 4><<<MBp * 4, 256, 0, stream>>>(
            Qb, wf1p + l * 65536, bf1 + l * 512, FFb, nullptr, nullptr, nullptr, nullptr, 0,
            nullptr, nullptr, nullptr, nullptr, nullptr, NN, 128, 512);
        gemm_bf16_kernel<3, true, false, 1, 0><<<MBp, 256, 0, stream>>>(
            FFb, wf2p + l * 65536, bf2 + l * 128, nullptr, nullptr, nullptr, nullptr, nullptr, 0,
            (const ushortT*)Qb, ln2g + l * 128, ln2b + l * 128,
            (l == LL - 1) ? fQ : nullptr, (__hip_bfloat16*)Qb, NN, 512, 128);
    }
    // ---- pool + head ----
    pool1_kernel<<<dim3(GG, 8), 128, 0, stream>>>(fQ, batch, psum, pmax, NN);
    pool2_kernel<<<GG, 128, 0, stream>>>(psum, pmax, batch, bn1g, bn1b, fHC, NN);
    head_kernel<<<GG, 64, 0, stream>>>(fHC, fc1w, fc1b, bn2g, bn2b, fc2w, fc2b, out);
}